// Round 1
// baseline (372.836 us; speedup 1.0000x reference)
//
#include <hip/hip_runtime.h>
#include <hip/hip_bf16.h>
#include <math.h>

#define NB 16
#define NLAT 512
#define NCTX 1024
#define CD 512
#define NH 8
#define HD 64

typedef unsigned short ushort_t;
typedef __attribute__((ext_vector_type(8))) __bf16 bf16x8;
typedef __attribute__((ext_vector_type(8))) unsigned short u16x8;
typedef __attribute__((ext_vector_type(4))) float f32x4;

__device__ __forceinline__ float bf2f(unsigned short u) {
  return __uint_as_float(((unsigned int)u) << 16);
}
__device__ __forceinline__ unsigned short f2bf(float f) {
  unsigned int x = __float_as_uint(f);
  return (unsigned short)((x + 0x7fffu + ((x >> 16) & 1u)) >> 16);
}
__device__ __forceinline__ float gelu_f(float x) {
  return 0.5f * x * (1.f + erff(x * 0.70710678118654752f));
}

typedef const __attribute__((address_space(1))) unsigned int* gptr1;
typedef __attribute__((address_space(3))) unsigned int* lptr3;
__device__ __forceinline__ void gload16(const void* g, void* l) {
  __builtin_amdgcn_global_load_lds((gptr1)g, (lptr3)l, 16, 0, 0);
}

// ---------------- weight transpose + bf16 convert: W (K,N) f32 -> WT (N,K) bf16
__global__ __launch_bounds__(256)
void wtrans_kernel(const float* __restrict__ W, ushort_t* __restrict__ WT, int K, int N) {
  __shared__ float tile[32][33];
  int kb = blockIdx.x * 32, nb = blockIdx.y * 32;
  int tx = threadIdx.x & 31, ty = threadIdx.x >> 5;  // ty 0..7
  for (int i = ty; i < 32; i += 8) {
    int k = kb + i, n = nb + tx;
    tile[i][tx] = (k < K && n < N) ? W[(size_t)k * N + n] : 0.f;
  }
  __syncthreads();
  for (int i = ty; i < 32; i += 8) {
    int n = nb + i, k = kb + tx;
    if (n < N && k < K) WT[(size_t)n * K + k] = f2bf(tile[tx][i]);
  }
}

// ---------------- LayerNorm (rows of 512), f32 in -> bf16 out. one wave per row.
__global__ __launch_bounds__(256)
void ln_kernel(const float* __restrict__ x, const float* __restrict__ gw,
               const float* __restrict__ gb, ushort_t* __restrict__ out, int nrows) {
  int row = blockIdx.x * 4 + (threadIdx.x >> 6);
  int lane = threadIdx.x & 63;
  const float4* xr = (const float4*)(x + (size_t)row * CD);
  float4 a = xr[lane * 2], b = xr[lane * 2 + 1];
  float s  = a.x + a.y + a.z + a.w + b.x + b.y + b.z + b.w;
  float s2 = a.x*a.x + a.y*a.y + a.z*a.z + a.w*a.w + b.x*b.x + b.y*b.y + b.z*b.z + b.w*b.w;
  for (int off = 32; off; off >>= 1) { s += __shfl_xor(s, off); s2 += __shfl_xor(s2, off); }
  float mean = s * (1.f / CD);
  float inv = rsqrtf(s2 * (1.f / CD) - mean * mean + 1e-5f);
  const float4* wv = (const float4*)gw;
  const float4* bv = (const float4*)gb;
  float4 w0 = wv[lane*2], w1 = wv[lane*2+1], c0 = bv[lane*2], c1 = bv[lane*2+1];
  u16x8 o;
  o[0] = f2bf((a.x - mean) * inv * w0.x + c0.x);
  o[1] = f2bf((a.y - mean) * inv * w0.y + c0.y);
  o[2] = f2bf((a.z - mean) * inv * w0.z + c0.z);
  o[3] = f2bf((a.w - mean) * inv * w0.w + c0.w);
  o[4] = f2bf((b.x - mean) * inv * w1.x + c1.x);
  o[5] = f2bf((b.y - mean) * inv * w1.y + c1.y);
  o[6] = f2bf((b.z - mean) * inv * w1.z + c1.z);
  o[7] = f2bf((b.w - mean) * inv * w1.w + c1.w);
  *(u16x8*)(out + (size_t)row * CD + lane * 8) = o;
}

// ---------------- generic bf16 MFMA GEMM: C = act(A(MxK) * BT(NxK)^T + bias) [+ res]
template<int ACT_GELU, int HAS_BIAS, int HAS_RES, int OUT_BF16>
__global__ __launch_bounds__(256)
void gemm_bf16(const ushort_t* __restrict__ A, const ushort_t* __restrict__ BT,
               const float* __restrict__ bias, const float* __restrict__ res,
               void* __restrict__ outp, int M, int N, int K) {
  __shared__ __attribute__((aligned(16))) ushort_t Als[2][128 * 32];
  __shared__ __attribute__((aligned(16))) ushort_t Bls[2][128 * 32];
  const int t = threadIdx.x;
  const int lane = t & 63;
  const int w = t >> 6, wr = w >> 1, wc = w & 1;
  const size_t m0 = (size_t)blockIdx.x * 128;
  const size_t n0 = (size_t)blockIdx.y * 128;
  const int r0 = t >> 2;
  const int ks = (t & 3) * 8;

  f32x4 acc[4][4] = {};

  const ushort_t* Ap = A + (m0 + r0) * K + ks;
  const ushort_t* Bp = BT + (n0 + r0) * K + ks;
  const int nK = K >> 5;

  auto stage = [&](int buf, int kt) {
    const size_t ko = (size_t)kt * 32;
    gload16(Ap + ko,             &Als[buf][t * 8]);
    gload16(Ap + (size_t)64 * K + ko, &Als[buf][2048 + t * 8]);
    gload16(Bp + ko,             &Bls[buf][t * 8]);
    gload16(Bp + (size_t)64 * K + ko, &Bls[buf][2048 + t * 8]);
  };
  auto compute = [&](int buf) {
    bf16x8 af[4], bfr[4];
    const int ksel = (lane >> 4) * 8;
#pragma unroll
    for (int m = 0; m < 4; m++)
      af[m] = *(const bf16x8*)&Als[buf][(wr * 64 + m * 16 + (lane & 15)) * 32 + ksel];
#pragma unroll
    for (int n = 0; n < 4; n++)
      bfr[n] = *(const bf16x8*)&Bls[buf][(wc * 64 + n * 16 + (lane & 15)) * 32 + ksel];
#pragma unroll
    for (int m = 0; m < 4; m++)
#pragma unroll
      for (int n = 0; n < 4; n++)
        acc[m][n] = __builtin_amdgcn_mfma_f32_16x16x32_bf16(af[m], bfr[n], acc[m][n], 0, 0, 0);
  };

  stage(0, 0);
  __syncthreads();
  int cur = 0;
  for (int kt = 0; kt < nK - 1; kt++) {
    stage(cur ^ 1, kt + 1);
    compute(cur);
    __syncthreads();
    cur ^= 1;
  }
  compute(cur);

  const int rowb = (int)m0 + wr * 64 + (lane >> 4) * 4;
  const int colb = (int)n0 + wc * 64 + (lane & 15);
#pragma unroll
  for (int n = 0; n < 4; n++) {
    int col = colb + n * 16;
    float bv = HAS_BIAS ? bias[col] : 0.f;
#pragma unroll
    for (int m = 0; m < 4; m++) {
#pragma unroll
      for (int r = 0; r < 4; r++) {
        size_t idx = (size_t)(rowb + m * 16 + r) * N + col;
        float v = acc[m][n][r];
        if (HAS_BIAS) v += bv;
        if (ACT_GELU) v = gelu_f(v);
        if (HAS_RES) v += res[idx];
        if (OUT_BF16) ((ushort_t*)outp)[idx] = f2bf(v);
        else          ((float*)outp)[idx] = v;
      }
    }
  }
}

// ---------------- gates: 3 matvec outputs per context row -> (B,3,HW) f32
__global__ __launch_bounds__(256)
void gates_kernel(const ushort_t* __restrict__ xc, const ushort_t* __restrict__ WfT,
                  const float* __restrict__ bfv, float* __restrict__ gates) {
  int row = blockIdx.x * 4 + (threadIdx.x >> 6);
  int lane = threadIdx.x & 63;
  u16x8 xv = *(const u16x8*)(xc + (size_t)row * CD + lane * 8);
  float xf[8];
#pragma unroll
  for (int e = 0; e < 8; e++) xf[e] = bf2f(xv[e]);
  float sl[3];
#pragma unroll
  for (int l = 0; l < 3; l++) {
    u16x8 wv = *(const u16x8*)(WfT + (size_t)(CD + l) * CD + lane * 8);
    float d = 0.f;
#pragma unroll
    for (int e = 0; e < 8; e++) d += xf[e] * bf2f(wv[e]);
    for (int off = 32; off; off >>= 1) d += __shfl_xor(d, off);
    sl[l] = d;
  }
  if (lane == 0) {
    int b = row >> 10, p = row & 1023;
#pragma unroll
    for (int l = 0; l < 3; l++) gates[((size_t)b * 3 + l) * 1024 + p] = sl[l] + bfv[CD + l];
  }
}

// ---------------- bf16 transpose per batch: in (R,C) -> out (C,R)
__global__ __launch_bounds__(256)
void tr_bf16(const ushort_t* __restrict__ in, ushort_t* __restrict__ out, int R, int C) {
  __shared__ ushort_t tile[64][72];
  size_t base = (size_t)blockIdx.z * R * C;
  int r0 = blockIdx.x * 64, c0 = blockIdx.y * 64;
  int t = threadIdx.x;
#pragma unroll
  for (int j = 0; j < 2; j++) {
    int lin = j * 256 + t;
    int r = lin >> 3, cc = (lin & 7) * 8;
    u16x8 v = *(const u16x8*)(in + base + (size_t)(r0 + r) * C + c0 + cc);
#pragma unroll
    for (int e = 0; e < 8; e++) tile[r][cc + e] = v[e];
  }
  __syncthreads();
#pragma unroll
  for (int j = 0; j < 2; j++) {
    int lin = j * 256 + t;
    int c = lin >> 3, rr = (lin & 7) * 8;
    u16x8 v;
#pragma unroll
    for (int e = 0; e < 8; e++) v[e] = tile[rr + e][c];
    *(u16x8*)(out + base + (size_t)(c0 + c) * R + r0 + rr) = v;
  }
}

// ---------------- focal depthwise convs + gating, one block per (b,c) 32x32 plane
__global__ __launch_bounds__(256)
void focal_conv(const ushort_t* __restrict__ ft, const float* __restrict__ gates,
                const float* __restrict__ fk0, const float* __restrict__ fk1,
                ushort_t* __restrict__ accc) {
  int bc = blockIdx.x;
  int b = bc >> 9, c = bc & 511;
  __shared__ float xs[1024];
  __shared__ float vs[1024];
  __shared__ float w0s[9], w1s[25];
  __shared__ float red[4];
  int t = threadIdx.x;
  const ushort_t* xp = ft + (size_t)bc * 1024;
#pragma unroll
  for (int i = 0; i < 4; i++) xs[t + i * 256] = bf2f(xp[t + i * 256]);
  if (t < 9)  w0s[t] = fk0[c * 9 + t];
  if (t < 25) w1s[t] = fk1[c * 25 + t];
  __syncthreads();
  const float* g0 = gates + (size_t)b * 3 * 1024;
  float accv[4];
#pragma unroll
  for (int i = 0; i < 4; i++) {
    int p = t + i * 256, hh = p >> 5, ww = p & 31;
    float s = 0.f;
#pragma unroll
    for (int dh = 0; dh < 3; dh++) {
      int y = hh + dh - 1;
      if ((unsigned)y >= 32u) continue;
#pragma unroll
      for (int dw = 0; dw < 3; dw++) {
        int xx = ww + dw - 1;
        if ((unsigned)xx >= 32u) continue;
        s += xs[y * 32 + xx] * w0s[dh * 3 + dw];
      }
    }
    float v1 = gelu_f(s);
    vs[p] = v1;
    accv[i] = v1 * g0[p];
  }
  __syncthreads();
  float psum = 0.f;
#pragma unroll
  for (int i = 0; i < 4; i++) {
    int p = t + i * 256, hh = p >> 5, ww = p & 31;
    float s = 0.f;
#pragma unroll
    for (int dh = 0; dh < 5; dh++) {
      int y = hh + dh - 2;
      if ((unsigned)y >= 32u) continue;
#pragma unroll
      for (int dw = 0; dw < 5; dw++) {
        int xx = ww + dw - 2;
        if ((unsigned)xx >= 32u) continue;
        s += vs[y * 32 + xx] * w1s[dh * 5 + dw];
      }
    }
    float v2 = gelu_f(s);
    psum += v2;
    accv[i] += v2 * g0[1024 + p];
  }
  for (int off = 32; off; off >>= 1) psum += __shfl_xor(psum, off);
  if ((t & 63) == 0) red[t >> 6] = psum;
  __syncthreads();
  float g = gelu_f((red[0] + red[1] + red[2] + red[3]) * (1.f / 1024.f));
  ushort_t* op = accc + (size_t)bc * 1024;
#pragma unroll
  for (int i = 0; i < 4; i++) {
    int p = t + i * 256;
    op[p] = f2bf(accv[i] + g * g0[2048 + p]);
  }
}

// ---------------- flash attention: 64 q rows/block, 4 waves x 16 rows, online softmax
__global__ __launch_bounds__(256)
void flash_attn(const ushort_t* __restrict__ Q, const ushort_t* __restrict__ Kk,
                const ushort_t* __restrict__ V, ushort_t* __restrict__ Y) {
  const int b = blockIdx.z, h = blockIdx.y;
  const int q0 = blockIdx.x * 64;
  const int t = threadIdx.x, lane = t & 63, w = t >> 6;
  __shared__ __attribute__((aligned(16))) ushort_t Ks[64 * 64];
  __shared__ __attribute__((aligned(16))) ushort_t Vt[64 * 72];
  __shared__ __attribute__((aligned(16))) ushort_t Ps[4][16 * 64];

  const size_t qbase = (((size_t)b * NLAT) + q0 + w * 16) * CD + h * HD;
  bf16x8 aq[2];
  {
    int row = lane & 15, kk = (lane >> 4) * 8;
    aq[0] = *(const bf16x8*)(Q + qbase + (size_t)row * CD + kk);
    aq[1] = *(const bf16x8*)(Q + qbase + (size_t)row * CD + 32 + kk);
  }
  f32x4 accO[4] = {};
  float mrow[4] = {-1e30f, -1e30f, -1e30f, -1e30f};
  float lrow[4] = {0.f, 0.f, 0.f, 0.f};
  const ushort_t* Kb = Kk + ((size_t)b * NCTX) * CD + h * HD;
  const ushort_t* Vb = V  + ((size_t)b * NCTX) * CD + h * HD;
  const int rowk = t >> 3, dseg = (t & 7) * 8;
  const int ksel = (lane >> 4) * 8;

  for (int kv = 0; kv < 16; kv++) {
    const int k0 = kv * 64;
    __syncthreads();
    gload16(Kb + (size_t)(k0 + rowk) * CD + dseg,      &Ks[t * 8]);
    gload16(Kb + (size_t)(k0 + 32 + rowk) * CD + dseg, &Ks[2048 + t * 8]);
    u16x8 v0 = *(const u16x8*)(Vb + (size_t)(k0 + rowk) * CD + dseg);
    u16x8 v1 = *(const u16x8*)(Vb + (size_t)(k0 + 32 + rowk) * CD + dseg);
#pragma unroll
    for (int e = 0; e < 8; e++) {
      Vt[(dseg + e) * 72 + rowk] = v0[e];
      Vt[(dseg + e) * 72 + 32 + rowk] = v1[e];
    }
    __syncthreads();

    f32x4 accS[4] = {};
#pragma unroll
    for (int kk = 0; kk < 2; kk++) {
#pragma unroll
      for (int n = 0; n < 4; n++) {
        bf16x8 bk = *(const bf16x8*)&Ks[(n * 16 + (lane & 15)) * 64 + kk * 32 + ksel];
        accS[n] = __builtin_amdgcn_mfma_f32_16x16x32_bf16(aq[kk], bk, accS[n], 0, 0, 0);
      }
    }
#pragma unroll
    for (int n = 0; n < 4; n++)
#pragma unroll
      for (int r = 0; r < 4; r++) accS[n][r] *= 0.125f;

#pragma unroll
    for (int r = 0; r < 4; r++) {
      float mx = fmaxf(fmaxf(accS[0][r], accS[1][r]), fmaxf(accS[2][r], accS[3][r]));
      mx = fmaxf(mx, __shfl_xor(mx, 1));
      mx = fmaxf(mx, __shfl_xor(mx, 2));
      mx = fmaxf(mx, __shfl_xor(mx, 4));
      mx = fmaxf(mx, __shfl_xor(mx, 8));
      float mnew = fmaxf(mrow[r], mx);
      float fr = __expf(mrow[r] - mnew);
      mrow[r] = mnew;
      float ps = 0.f;
#pragma unroll
      for (int n = 0; n < 4; n++) {
        float p = __expf(accS[n][r] - mnew);
        accS[n][r] = p;
        ps += p;
      }
      ps += __shfl_xor(ps, 1); ps += __shfl_xor(ps, 2);
      ps += __shfl_xor(ps, 4); ps += __shfl_xor(ps, 8);
      lrow[r] = lrow[r] * fr + ps;
#pragma unroll
      for (int n = 0; n < 4; n++) accO[n][r] *= fr;
    }
#pragma unroll
    for (int n = 0; n < 4; n++)
#pragma unroll
      for (int r = 0; r < 4; r++)
        Ps[w][((lane >> 4) * 4 + r) * 64 + n * 16 + (lane & 15)] = f2bf(accS[n][r]);
    asm volatile("s_waitcnt lgkmcnt(0)" ::: "memory");
    bf16x8 ap0 = *(const bf16x8*)&Ps[w][(lane & 15) * 64 + ksel];
    bf16x8 ap1 = *(const bf16x8*)&Ps[w][(lane & 15) * 64 + 32 + ksel];
#pragma unroll
    for (int n = 0; n < 4; n++) {
      bf16x8 bv0 = *(const bf16x8*)&Vt[(n * 16 + (lane & 15)) * 72 + ksel];
      bf16x8 bv1 = *(const bf16x8*)&Vt[(n * 16 + (lane & 15)) * 72 + 32 + ksel];
      accO[n] = __builtin_amdgcn_mfma_f32_16x16x32_bf16(ap0, bv0, accO[n], 0, 0, 0);
      accO[n] = __builtin_amdgcn_mfma_f32_16x16x32_bf16(ap1, bv1, accO[n], 0, 0, 0);
    }
  }
#pragma unroll
  for (int r = 0; r < 4; r++) lrow[r] = 1.f / lrow[r];
#pragma unroll
  for (int n = 0; n < 4; n++) {
#pragma unroll
    for (int r = 0; r < 4; r++) {
      size_t row = q0 + w * 16 + (lane >> 4) * 4 + r;
      size_t col = h * HD + n * 16 + (lane & 15);
      Y[(((size_t)b * NLAT) + row) * CD + col] = f2bf(accO[n][r] * lrow[r]);
    }
  }
}

// ---------------- host orchestration
extern "C" void kernel_launch(void* const* d_in, const int* in_sizes, int n_in,
                              void* d_out, int out_size, void* d_ws, size_t ws_size,
                              hipStream_t stream) {
  const float* latents  = (const float*)d_in[0];
  const float* context  = (const float*)d_in[1];
  const float* norm_l_w = (const float*)d_in[4];
  const float* norm_l_b = (const float*)d_in[5];
  const float* norm_c_w = (const float*)d_in[6];
  const float* norm_c_b = (const float*)d_in[7];
  const float* norm2_w  = (const float*)d_in[8];
  const float* norm2_b  = (const float*)d_in[9];
  const float* Wq    = (const float*)d_in[10];
  const float* Wk    = (const float*)d_in[11];
  const float* Wf    = (const float*)d_in[12];
  const float* bfv   = (const float*)d_in[13];
  const float* fk0   = (const float*)d_in[14];
  const float* fk1   = (const float*)d_in[15];
  const float* h_w   = (const float*)d_in[16];
  const float* h_b   = (const float*)d_in[17];
  const float* Wproj = (const float*)d_in[18];
  const float* bproj = (const float*)d_in[19];
  const float* fc1_w = (const float*)d_in[20];
  const float* fc1_b = (const float*)d_in[21];
  const float* fc2_w = (const float*)d_in[22];
  const float* fc2_b = (const float*)d_in[23];

  char* ws = (char*)d_ws;
  const size_t MB = 1024ull * 1024ull;
  // weights (bf16, transposed), [0, 10MB)
  ushort_t* WqT  = (ushort_t*)(ws + 0 * MB);
  ushort_t* WkT  = (ushort_t*)(ws + 1 * MB);
  ushort_t* WfT  = (ushort_t*)(ws + 2 * MB);   // 515 x 512
  ushort_t* hwT  = (ushort_t*)(ws + 3 * MB);
  ushort_t* WpT  = (ushort_t*)(ws + 4 * MB);
  ushort_t* fc1T = (ushort_t*)(ws + 5 * MB);   // 2048 x 512
  ushort_t* fc2T = (ushort_t*)(ws + 7 * MB);   // 512 x 2048
  // activations
  ushort_t* xl    = (ushort_t*)(ws + 10 * MB);  // 8192 x 512
  ushort_t* xc    = (ushort_t*)(ws + 18 * MB);  // 16384 x 512
  ushort_t* qb    = (ushort_t*)(ws + 34 * MB);  // 8192 x 512
  ushort_t* kb    = (ushort_t*)(ws + 42 * MB);  // 16384 x 512
  ushort_t* fv    = (ushort_t*)(ws + 58 * MB);  // 16384 x 512  (B,HW,C)
  float*    gates = (float*)   (ws + 74 * MB);  // B x 3 x 1024
  ushort_t* ftp   = (ushort_t*)(ws + 75 * MB);  // (B,C,HW)
  ushort_t* accc  = (ushort_t*)(ws + 91 * MB);  // (B,C,HW)
  ushort_t* acct  = (ushort_t*)(ws + 58 * MB);  // (B,HW,C)  reuse fv
  ushort_t* vb    = (ushort_t*)(ws + 75 * MB);  // reuse ftp
  ushort_t* yb    = (ushort_t*)(ws + 91 * MB);  // reuse accc
  float*    lat1  = (float*)   (ws + 99 * MB);  // 8192 x 512 f32
  ushort_t* h2    = (ushort_t*)(ws + 10 * MB);  // reuse xl
  ushort_t* a1    = (ushort_t*)(ws + 18 * MB);  // 8192 x 2048, reuse xc/q/k

  dim3 b256(256);
  // 1. weight prep
  wtrans_kernel<<<dim3(16, 16), b256, 0, stream>>>(Wq,    WqT,  512, 512);
  wtrans_kernel<<<dim3(16, 16), b256, 0, stream>>>(Wk,    WkT,  512, 512);
  wtrans_kernel<<<dim3(16, 17), b256, 0, stream>>>(Wf,    WfT,  512, 515);
  wtrans_kernel<<<dim3(16, 16), b256, 0, stream>>>(h_w,   hwT,  512, 512);
  wtrans_kernel<<<dim3(16, 16), b256, 0, stream>>>(Wproj, WpT,  512, 512);
  wtrans_kernel<<<dim3(16, 64), b256, 0, stream>>>(fc1_w, fc1T, 512, 2048);
  wtrans_kernel<<<dim3(64, 16), b256, 0, stream>>>(fc2_w, fc2T, 2048, 512);
  // 2. layernorms
  ln_kernel<<<dim3(2048), b256, 0, stream>>>(latents, norm_l_w, norm_l_b, xl, 8192);
  ln_kernel<<<dim3(4096), b256, 0, stream>>>(context, norm_c_w, norm_c_b, xc, 16384);
  // 3. q,k,f projections
  gemm_bf16<0,0,0,1><<<dim3(64, 4),  b256, 0, stream>>>(xl, WqT, nullptr, nullptr, qb, 8192, 512, 512);
  gemm_bf16<0,0,0,1><<<dim3(128, 4), b256, 0, stream>>>(xc, WkT, nullptr, nullptr, kb, 16384, 512, 512);
  gemm_bf16<0,1,0,1><<<dim3(128, 4), b256, 0, stream>>>(xc, WfT, bfv, nullptr, fv, 16384, 512, 512);
  gates_kernel<<<dim3(4096), b256, 0, stream>>>(xc, WfT, bfv, gates);
  // 4. focal modulation branch
  tr_bf16<<<dim3(16, 8, 16), b256, 0, stream>>>(fv, ftp, 1024, 512);
  focal_conv<<<dim3(8192), b256, 0, stream>>>(ftp, gates, fk0, fk1, accc);
  tr_bf16<<<dim3(8, 16, 16), b256, 0, stream>>>(accc, acct, 512, 1024);
  gemm_bf16<0,1,0,1><<<dim3(128, 4), b256, 0, stream>>>(acct, hwT, h_b, nullptr, vb, 16384, 512, 512);
  // 5. attention + proj (+ residual)
  flash_attn<<<dim3(8, 8, 16), b256, 0, stream>>>(qb, kb, vb, yb);
  gemm_bf16<0,1,1,0><<<dim3(64, 4), b256, 0, stream>>>(yb, WpT, bproj, latents, lat1, 8192, 512, 512);
  // 6. MLP (+ residual) -> d_out (f32)
  ln_kernel<<<dim3(2048), b256, 0, stream>>>(lat1, norm2_w, norm2_b, h2, 8192);
  gemm_bf16<1,1,0,1><<<dim3(64, 16), b256, 0, stream>>>(h2, fc1T, fc1_b, nullptr, a1, 8192, 2048, 512);
  gemm_bf16<0,1,1,0><<<dim3(64, 4),  b256, 0, stream>>>(a1, fc2T, fc2_b, lat1, d_out, 8192, 512, 2048);
  (void)in_sizes; (void)n_in; (void)out_size; (void)ws_size;
}

// Round 2
// 333.474 us; speedup vs baseline: 1.1180x; 1.1180x over previous
//
#include <hip/hip_runtime.h>
#include <hip/hip_bf16.h>
#include <math.h>

#define NB 16
#define NLAT 512
#define NCTX 1024
#define CD 512
#define NH 8
#define HD 64

typedef unsigned short ushort_t;
typedef __attribute__((ext_vector_type(8))) __bf16 bf16x8;
typedef __attribute__((ext_vector_type(8))) unsigned short u16x8;
typedef __attribute__((ext_vector_type(4))) float f32x4;
typedef __attribute__((ext_vector_type(2))) unsigned int u32x2;

__device__ __forceinline__ float bf2f(unsigned short u) {
  return __uint_as_float(((unsigned int)u) << 16);
}
__device__ __forceinline__ unsigned short f2bf(float f) {
  unsigned int x = __float_as_uint(f);
  return (unsigned short)((x + 0x7fffu + ((x >> 16) & 1u)) >> 16);
}
__device__ __forceinline__ float gelu_f(float x) {
  return 0.5f * x * (1.f + erff(x * 0.70710678118654752f));
}

typedef const __attribute__((address_space(1))) unsigned int* gptr1;
typedef __attribute__((address_space(3))) unsigned int* lptr3;
__device__ __forceinline__ void gload16(const void* g, void* l) {
  __builtin_amdgcn_global_load_lds((gptr1)g, (lptr3)l, 16, 0, 0);
}
__device__ __forceinline__ u32x2 tr64(unsigned a) {
  u32x2 d;
  asm volatile("ds_read_b64_tr_b16 %0, %1" : "=v"(d) : "v"(a));
  return d;
}

// ---------------- weight transpose + bf16 convert: W (K,N) f32 -> WT (N,K) bf16
__global__ __launch_bounds__(256)
void wtrans_kernel(const float* __restrict__ W, ushort_t* __restrict__ WT, int K, int N) {
  __shared__ float tile[32][33];
  int kb = blockIdx.x * 32, nb = blockIdx.y * 32;
  int tx = threadIdx.x & 31, ty = threadIdx.x >> 5;  // ty 0..7
  for (int i = ty; i < 32; i += 8) {
    int k = kb + i, n = nb + tx;
    tile[i][tx] = (k < K && n < N) ? W[(size_t)k * N + n] : 0.f;
  }
  __syncthreads();
  for (int i = ty; i < 32; i += 8) {
    int n = nb + i, k = kb + tx;
    if (n < N && k < K) WT[(size_t)n * K + k] = f2bf(tile[tx][i]);
  }
}

// ---------------- LayerNorm (rows of 512), f32 in -> bf16 out. one wave per row.
__global__ __launch_bounds__(256)
void ln_kernel(const float* __restrict__ x, const float* __restrict__ gw,
               const float* __restrict__ gb, ushort_t* __restrict__ out, int nrows) {
  int row = blockIdx.x * 4 + (threadIdx.x >> 6);
  int lane = threadIdx.x & 63;
  const float4* xr = (const float4*)(x + (size_t)row * CD);
  float4 a = xr[lane * 2], b = xr[lane * 2 + 1];
  float s  = a.x + a.y + a.z + a.w + b.x + b.y + b.z + b.w;
  float s2 = a.x*a.x + a.y*a.y + a.z*a.z + a.w*a.w + b.x*b.x + b.y*b.y + b.z*b.z + b.w*b.w;
  for (int off = 32; off; off >>= 1) { s += __shfl_xor(s, off); s2 += __shfl_xor(s2, off); }
  float mean = s * (1.f / CD);
  float inv = rsqrtf(s2 * (1.f / CD) - mean * mean + 1e-5f);
  const float4* wv = (const float4*)gw;
  const float4* bv = (const float4*)gb;
  float4 w0 = wv[lane*2], w1 = wv[lane*2+1], c0 = bv[lane*2], c1 = bv[lane*2+1];
  u16x8 o;
  o[0] = f2bf((a.x - mean) * inv * w0.x + c0.x);
  o[1] = f2bf((a.y - mean) * inv * w0.y + c0.y);
  o[2] = f2bf((a.z - mean) * inv * w0.z + c0.z);
  o[3] = f2bf((a.w - mean) * inv * w0.w + c0.w);
  o[4] = f2bf((b.x - mean) * inv * w1.x + c1.x);
  o[5] = f2bf((b.y - mean) * inv * w1.y + c1.y);
  o[6] = f2bf((b.z - mean) * inv * w1.z + c1.z);
  o[7] = f2bf((b.w - mean) * inv * w1.w + c1.w);
  *(u16x8*)(out + (size_t)row * CD + lane * 8) = o;
  (void)nrows;
}

// ---------------- generic bf16 MFMA GEMM: C = act(A(MxK) * BT(NxK)^T + bias) [+ res]
template<int ACT_GELU, int HAS_BIAS, int HAS_RES, int OUT_BF16>
__global__ __launch_bounds__(256)
void gemm_bf16(const ushort_t* __restrict__ A, const ushort_t* __restrict__ BT,
               const float* __restrict__ bias, const float* __restrict__ res,
               void* __restrict__ outp, int M, int N, int K) {
  __shared__ __attribute__((aligned(16))) ushort_t Als[2][128 * 32];
  __shared__ __attribute__((aligned(16))) ushort_t Bls[2][128 * 32];
  const int t = threadIdx.x;
  const int lane = t & 63;
  const int w = t >> 6, wr = w >> 1, wc = w & 1;
  const size_t m0 = (size_t)blockIdx.x * 128;
  const size_t n0 = (size_t)blockIdx.y * 128;
  const int r0 = t >> 2;
  const int ks = (t & 3) * 8;

  f32x4 acc[4][4] = {};

  const ushort_t* Ap = A + (m0 + r0) * K + ks;
  const ushort_t* Bp = BT + (n0 + r0) * K + ks;
  const int nK = K >> 5;

  auto stage = [&](int buf, int kt) {
    const size_t ko = (size_t)kt * 32;
    gload16(Ap + ko,             &Als[buf][t * 8]);
    gload16(Ap + (size_t)64 * K + ko, &Als[buf][2048 + t * 8]);
    gload16(Bp + ko,             &Bls[buf][t * 8]);
    gload16(Bp + (size_t)64 * K + ko, &Bls[buf][2048 + t * 8]);
  };
  auto compute = [&](int buf) {
    bf16x8 af[4], bfr[4];
    const int ksel = (lane >> 4) * 8;
#pragma unroll
    for (int m = 0; m < 4; m++)
      af[m] = *(const bf16x8*)&Als[buf][(wr * 64 + m * 16 + (lane & 15)) * 32 + ksel];
#pragma unroll
    for (int n = 0; n < 4; n++)
      bfr[n] = *(const bf16x8*)&Bls[buf][(wc * 64 + n * 16 + (lane & 15)) * 32 + ksel];
#pragma unroll
    for (int m = 0; m < 4; m++)
#pragma unroll
      for (int n = 0; n < 4; n++)
        acc[m][n] = __builtin_amdgcn_mfma_f32_16x16x32_bf16(af[m], bfr[n], acc[m][n], 0, 0, 0);
  };

  stage(0, 0);
  __syncthreads();
  int cur = 0;
  for (int kt = 0; kt < nK - 1; kt++) {
    stage(cur ^ 1, kt + 1);
    compute(cur);
    __syncthreads();
    cur ^= 1;
  }
  compute(cur);

  const int rowb = (int)m0 + wr * 64 + (lane >> 4) * 4;
  const int colb = (int)n0 + wc * 64 + (lane & 15);
#pragma unroll
  for (int n = 0; n < 4; n++) {
    int col = colb + n * 16;
    float bv = HAS_BIAS ? bias[col] : 0.f;
#pragma unroll
    for (int m = 0; m < 4; m++) {
#pragma unroll
      for (int r = 0; r < 4; r++) {
        size_t idx = (size_t)(rowb + m * 16 + r) * N + col;
        float v = acc[m][n][r];
        if (HAS_BIAS) v += bv;
        if (ACT_GELU) v = gelu_f(v);
        if (HAS_RES) v += res[idx];
        if (OUT_BF16) ((ushort_t*)outp)[idx] = f2bf(v);
        else          ((float*)outp)[idx] = v;
      }
    }
  }
}

// ---------------- gates: 3 matvec outputs per context row -> (B,3,HW) f32
__global__ __launch_bounds__(256)
void gates_kernel(const ushort_t* __restrict__ xc, const ushort_t* __restrict__ WfT,
                  const float* __restrict__ bfv, float* __restrict__ gates) {
  int row = blockIdx.x * 4 + (threadIdx.x >> 6);
  int lane = threadIdx.x & 63;
  u16x8 xv = *(const u16x8*)(xc + (size_t)row * CD + lane * 8);
  float xf[8];
#pragma unroll
  for (int e = 0; e < 8; e++) xf[e] = bf2f(xv[e]);
  float sl[3];
#pragma unroll
  for (int l = 0; l < 3; l++) {
    u16x8 wv = *(const u16x8*)(WfT + (size_t)(CD + l) * CD + lane * 8);
    float d = 0.f;
#pragma unroll
    for (int e = 0; e < 8; e++) d += xf[e] * bf2f(wv[e]);
    for (int off = 32; off; off >>= 1) d += __shfl_xor(d, off);
    sl[l] = d;
  }
  if (lane == 0) {
    int b = row >> 10, p = row & 1023;
#pragma unroll
    for (int l = 0; l < 3; l++) gates[((size_t)b * 3 + l) * 1024 + p] = sl[l] + bfv[CD + l];
  }
}

// ---------------- bf16 transpose per batch: in (R,C) -> out (C,R)
__global__ __launch_bounds__(256)
void tr_bf16(const ushort_t* __restrict__ in, ushort_t* __restrict__ out, int R, int C) {
  __shared__ ushort_t tile[64][72];
  size_t base = (size_t)blockIdx.z * R * C;
  int r0 = blockIdx.x * 64, c0 = blockIdx.y * 64;
  int t = threadIdx.x;
#pragma unroll
  for (int j = 0; j < 2; j++) {
    int lin = j * 256 + t;
    int r = lin >> 3, cc = (lin & 7) * 8;
    u16x8 v = *(const u16x8*)(in + base + (size_t)(r0 + r) * C + c0 + cc);
#pragma unroll
    for (int e = 0; e < 8; e++) tile[r][cc + e] = v[e];
  }
  __syncthreads();
#pragma unroll
  for (int j = 0; j < 2; j++) {
    int lin = j * 256 + t;
    int c = lin >> 3, rr = (lin & 7) * 8;
    u16x8 v;
#pragma unroll
    for (int e = 0; e < 8; e++) v[e] = tile[rr + e][c];
    *(u16x8*)(out + base + (size_t)(c0 + c) * R + r0 + rr) = v;
  }
}

// ---------------- focal depthwise convs + gating, one block per (b,c) 32x32 plane
__global__ __launch_bounds__(256)
void focal_conv(const ushort_t* __restrict__ ft, const float* __restrict__ gates,
                const float* __restrict__ fk0, const float* __restrict__ fk1,
                ushort_t* __restrict__ accc) {
  int bc = blockIdx.x;
  int b = bc >> 9, c = bc & 511;
  __shared__ float xs[1024];
  __shared__ float vs[1024];
  __shared__ float w0s[9], w1s[25];
  __shared__ float red[4];
  int t = threadIdx.x;
  const ushort_t* xp = ft + (size_t)bc * 1024;
#pragma unroll
  for (int i = 0; i < 4; i++) xs[t + i * 256] = bf2f(xp[t + i * 256]);
  if (t < 9)  w0s[t] = fk0[c * 9 + t];
  if (t < 25) w1s[t] = fk1[c * 25 + t];
  __syncthreads();
  const float* g0 = gates + (size_t)b * 3 * 1024;
  float accv[4];
#pragma unroll
  for (int i = 0; i < 4; i++) {
    int p = t + i * 256, hh = p >> 5, ww = p & 31;
    float s = 0.f;
#pragma unroll
    for (int dh = 0; dh < 3; dh++) {
      int y = hh + dh - 1;
      if ((unsigned)y >= 32u) continue;
#pragma unroll
      for (int dw = 0; dw < 3; dw++) {
        int xx = ww + dw - 1;
        if ((unsigned)xx >= 32u) continue;
        s += xs[y * 32 + xx] * w0s[dh * 3 + dw];
      }
    }
    float v1 = gelu_f(s);
    vs[p] = v1;
    accv[i] = v1 * g0[p];
  }
  __syncthreads();
  float psum = 0.f;
#pragma unroll
  for (int i = 0; i < 4; i++) {
    int p = t + i * 256, hh = p >> 5, ww = p & 31;
    float s = 0.f;
#pragma unroll
    for (int dh = 0; dh < 5; dh++) {
      int y = hh + dh - 2;
      if ((unsigned)y >= 32u) continue;
#pragma unroll
      for (int dw = 0; dw < 5; dw++) {
        int xx = ww + dw - 2;
        if ((unsigned)xx >= 32u) continue;
        s += vs[y * 32 + xx] * w1s[dh * 5 + dw];
      }
    }
    float v2 = gelu_f(s);
    psum += v2;
    accv[i] += v2 * g0[1024 + p];
  }
  for (int off = 32; off; off >>= 1) psum += __shfl_xor(psum, off);
  if ((t & 63) == 0) red[t >> 6] = psum;
  __syncthreads();
  float g = gelu_f((red[0] + red[1] + red[2] + red[3]) * (1.f / 1024.f));
  ushort_t* op = accc + (size_t)bc * 1024;
#pragma unroll
  for (int i = 0; i < 4; i++) {
    int p = t + i * 256;
    op[p] = f2bf(accv[i] + g * g0[2048 + p]);
  }
}

// ---------------- flash attention v2: 128 q rows/block, 8 waves, swizzled K,
// subtiled V + ds_read_b64_tr_b16, double-buffered K/V staging
__global__ __launch_bounds__(512)
void flash_attn(const ushort_t* __restrict__ Q, const ushort_t* __restrict__ Kk,
                const ushort_t* __restrict__ V, ushort_t* __restrict__ Y) {
  const int b = blockIdx.z, h = blockIdx.y;
  const int q0 = blockIdx.x * 128;
  const int t = threadIdx.x, lane = t & 63, w = t >> 6;
  const int g = lane >> 4, l15 = lane & 15;
  // Ks: logical [64 k][64 d], byte = k*128 + (colbyte ^ ((k&7)<<4))
  __shared__ __attribute__((aligned(16))) ushort_t Ks[2][4096];
  // Vs: subtiled [s=d>>4][k][d&15], element (k,d) at (d>>4)*1024 + k*16 + (d&15)
  __shared__ __attribute__((aligned(16))) ushort_t Vs[2][4096];
  // Ps: per-wave logical [16 q][64 k], byte = q*128 + (colbyte ^ ((q&7)<<4))
  __shared__ __attribute__((aligned(16))) ushort_t Ps[8][1024];

  // Q fragments for this wave's 16 rows, pre-scaled by 1/sqrt(hd)=0.125
  const size_t qbase = (((size_t)b * NLAT) + q0 + w * 16 + l15) * CD + h * HD;
  bf16x8 aq[2];
#pragma unroll
  for (int kk = 0; kk < 2; kk++) {
    u16x8 u = *(const u16x8*)(Q + qbase + kk * 32 + g * 8);
    u16x8 o;
#pragma unroll
    for (int e = 0; e < 8; e++) o[e] = f2bf(bf2f(u[e]) * 0.125f);
    aq[kk] = *(bf16x8*)&o;
  }

  f32x4 accO[4] = {};
  float mrow[4] = {-1e30f, -1e30f, -1e30f, -1e30f};
  float lrow[4] = {0.f, 0.f, 0.f, 0.f};
  const ushort_t* Kb = Kk + ((size_t)b * NCTX) * CD + h * HD;
  const ushort_t* Vb = V  + ((size_t)b * NCTX) * CD + h * HD;
  // staging source offsets (pre-swizzled so linear LDS dest = swizzled layout)
  const int krow = t >> 3;
  const int kseg = 8 * ((t & 7) ^ (krow & 7));          // K: inverse of read swizzle
  const int vrow = (t >> 1) & 63;
  const int vcol = (t >> 7) * 16 + (t & 1) * 8;         // V: subtile pre-permute

  auto stage = [&](int buf, int kv) {
    const int k0 = kv * 64;
    gload16(Kb + (size_t)(k0 + krow) * CD + kseg, &Ks[buf][t * 8]);
    gload16(Vb + (size_t)(k0 + vrow) * CD + vcol, &Vs[buf][t * 8]);
  };

  const unsigned vsbase0 = (unsigned)(size_t)(lptr3)&Vs[0][0];
  const unsigned vsbase1 = (unsigned)(size_t)(lptr3)&Vs[1][0];
  char* psb = (char*)&Ps[w][0];

  stage(0, 0);
  __syncthreads();
  int cur = 0;
  for (int kv = 0; kv < 16; kv++) {
    if (kv < 15) stage(cur ^ 1, kv + 1);

    // ---- QK^T : S[16q x 64k] ----
    const char* ksb = (const char*)&Ks[cur][0];
    f32x4 accS[4] = {};
#pragma unroll
    for (int kk = 0; kk < 2; kk++) {
#pragma unroll
      for (int n = 0; n < 4; n++) {
        int rr = n * 16 + l15;
        bf16x8 bk = *(const bf16x8*)(ksb + rr * 128 + ((kk * 64 + g * 16) ^ ((rr & 7) << 4)));
        accS[n] = __builtin_amdgcn_mfma_f32_16x16x32_bf16(aq[kk], bk, accS[n], 0, 0, 0);
      }
    }

    // ---- online softmax (rows q = g*4+r, cols k across n and 16 lanes) ----
#pragma unroll
    for (int r = 0; r < 4; r++) {
      float mx = fmaxf(fmaxf(accS[0][r], accS[1][r]), fmaxf(accS[2][r], accS[3][r]));
      mx = fmaxf(mx, __shfl_xor(mx, 1));
      mx = fmaxf(mx, __shfl_xor(mx, 2));
      mx = fmaxf(mx, __shfl_xor(mx, 4));
      mx = fmaxf(mx, __shfl_xor(mx, 8));
      float mnew = fmaxf(mrow[r], mx);
      float fr = __expf(mrow[r] - mnew);
      mrow[r] = mnew;
      float ps = 0.f;
#pragma unroll
      for (int n = 0; n < 4; n++) {
        float p = __expf(accS[n][r] - mnew);
        accS[n][r] = p;
        ps += p;
      }
      ps += __shfl_xor(ps, 1); ps += __shfl_xor(ps, 2);
      ps += __shfl_xor(ps, 4); ps += __shfl_xor(ps, 8);
      lrow[r] = lrow[r] * fr + ps;
#pragma unroll
      for (int n = 0; n < 4; n++) accO[n][r] *= fr;
    }

    // ---- P -> LDS (swizzled), per-wave private ----
#pragma unroll
    for (int n = 0; n < 4; n++) {
#pragma unroll
      for (int r = 0; r < 4; r++) {
        int row = g * 4 + r;
        int cb = (n * 16 + l15) * 2;
        *(ushort_t*)(psb + row * 128 + (cb ^ ((row & 7) << 4))) = f2bf(accS[n][r]);
      }
    }
    asm volatile("s_waitcnt lgkmcnt(0)" ::: "memory");
    __builtin_amdgcn_sched_barrier(0);
    bf16x8 ap0 = *(const bf16x8*)(psb + l15 * 128 + (((g * 16)) ^ ((l15 & 7) << 4)));
    bf16x8 ap1 = *(const bf16x8*)(psb + l15 * 128 + ((64 + g * 16) ^ ((l15 & 7) << 4)));

    // ---- PV via hardware transpose reads ----
    const unsigned vsb = (cur ? vsbase1 : vsbase0) + g * 128;
#pragma unroll
    for (int n = 0; n < 4; n++) {
      union { u32x2 d2[2]; bf16x8 v; } pk0, pk1;
      unsigned a = vsb + n * 2048;
      pk0.d2[0] = tr64(a);
      pk0.d2[1] = tr64(a + 128);
      pk1.d2[0] = tr64(a + 1024);
      pk1.d2[1] = tr64(a + 1152);
      asm volatile("s_waitcnt lgkmcnt(0)" ::: "memory");
      __builtin_amdgcn_sched_barrier(0);
      accO[n] = __builtin_amdgcn_mfma_f32_16x16x32_bf16(ap0, pk0.v, accO[n], 0, 0, 0);
      accO[n] = __builtin_amdgcn_mfma_f32_16x16x32_bf16(ap1, pk1.v, accO[n], 0, 0, 0);
    }
    __syncthreads();
    cur ^= 1;
  }

#pragma unroll
  for (int r = 0; r < 4; r++) lrow[r] = 1.f / lrow[r];
#pragma unroll
  for (int n = 0; n < 4; n++) {
#pragma unroll
    for (int r = 0; r < 4; r++) {
      size_t row = q0 + w * 16 + g * 4 + r;
      size_t col = h * HD + n * 16 + l15;
      Y[(((size_t)b * NLAT) + row) * CD + col] = f2bf(accO[n][r] * lrow[r]);
    }
  }
}

// ---------------- host orchestration
extern "C" void kernel_launch(void* const* d_in, const int* in_sizes, int n_in,
                              void* d_out, int out_size, void* d_ws, size_t ws_size,
                              hipStream_t stream) {
  const float* latents  = (const float*)d_in[0];
  const float* context  = (const float*)d_in[1];
  const float* norm_l_w = (const float*)d_in[4];
  const float* norm_l_b = (const float*)d_in[5];
  const float* norm_c_w = (const float*)d_in[6];
  const float* norm_c_b = (const float*)d_in[7];
  const float* norm2_w  = (const float*)d_in[8];
  const float* norm2_b  = (const float*)d_in[9];
  const float* Wq    = (const float*)d_in[10];
  const float* Wk    = (const float*)d_in[11];
  const float* Wf    = (const float*)d_in[12];
  const float* bfv   = (const float*)d_in[13];
  const float* fk0   = (const float*)d_in[14];
  const float* fk1   = (const float*)d_in[15];
  const float* h_w   = (const float*)d_in[16];
  const float* h_b   = (const float*)d_in[17];
  const float* Wproj = (const float*)d_in[18];
  const float* bproj = (const float*)d_in[19];
  const float* fc1_w = (const float*)d_in[20];
  const float* fc1_b = (const float*)d_in[21];
  const float* fc2_w = (const float*)d_in[22];
  const float* fc2_b = (const float*)d_in[23];

  char* ws = (char*)d_ws;
  const size_t MB = 1024ull * 1024ull;
  // weights (bf16, transposed), [0, 10MB)
  ushort_t* WqT  = (ushort_t*)(ws + 0 * MB);
  ushort_t* WkT  = (ushort_t*)(ws + 1 * MB);
  ushort_t* WfT  = (ushort_t*)(ws + 2 * MB);   // 515 x 512
  ushort_t* hwT  = (ushort_t*)(ws + 3 * MB);
  ushort_t* WpT  = (ushort_t*)(ws + 4 * MB);
  ushort_t* fc1T = (ushort_t*)(ws + 5 * MB);   // 2048 x 512
  ushort_t* fc2T = (ushort_t*)(ws + 7 * MB);   // 512 x 2048
  // activations
  ushort_t* xl    = (ushort_t*)(ws + 10 * MB);  // 8192 x 512
  ushort_t* xc    = (ushort_t*)(ws + 18 * MB);  // 16384 x 512
  ushort_t* qb    = (ushort_t*)(ws + 34 * MB);  // 8192 x 512
  ushort_t* kb    = (ushort_t*)(ws + 42 * MB);  // 16384 x 512
  ushort_t* fv    = (ushort_t*)(ws + 58 * MB);  // 16384 x 512  (B,HW,C)
  float*    gates = (float*)   (ws + 74 * MB);  // B x 3 x 1024
  ushort_t* ftp   = (ushort_t*)(ws + 75 * MB);  // (B,C,HW)
  ushort_t* accc  = (ushort_t*)(ws + 91 * MB);  // (B,C,HW)
  ushort_t* acct  = (ushort_t*)(ws + 58 * MB);  // (B,HW,C)  reuse fv
  ushort_t* vb    = (ushort_t*)(ws + 75 * MB);  // reuse ftp
  ushort_t* yb    = (ushort_t*)(ws + 91 * MB);  // reuse accc
  float*    lat1  = (float*)   (ws + 99 * MB);  // 8192 x 512 f32
  ushort_t* h2    = (ushort_t*)(ws + 10 * MB);  // reuse xl
  ushort_t* a1    = (ushort_t*)(ws + 18 * MB);  // 8192 x 2048, reuse xc/q/k

  dim3 b256(256);
  // 1. weight prep
  wtrans_kernel<<<dim3(16, 16), b256, 0, stream>>>(Wq,    WqT,  512, 512);
  wtrans_kernel<<<dim3(16, 16), b256, 0, stream>>>(Wk,    WkT,  512, 512);
  wtrans_kernel<<<dim3(16, 17), b256, 0, stream>>>(Wf,    WfT,  512, 515);
  wtrans_kernel<<<dim3(16, 16), b256, 0, stream>>>(h_w,   hwT,  512, 512);
  wtrans_kernel<<<dim3(16, 16), b256, 0, stream>>>(Wproj, WpT,  512, 512);
  wtrans_kernel<<<dim3(16, 64), b256, 0, stream>>>(fc1_w, fc1T, 512, 2048);
  wtrans_kernel<<<dim3(64, 16), b256, 0, stream>>>(fc2_w, fc2T, 2048, 512);
  // 2. layernorms
  ln_kernel<<<dim3(2048), b256, 0, stream>>>(latents, norm_l_w, norm_l_b, xl, 8192);
  ln_kernel<<<dim3(4096), b256, 0, stream>>>(context, norm_c_w, norm_c_b, xc, 16384);
  // 3. q,k,f projections
  gemm_bf16<0,0,0,1><<<dim3(64, 4),  b256, 0, stream>>>(xl, WqT, nullptr, nullptr, qb, 8192, 512, 512);
  gemm_bf16<0,0,0,1><<<dim3(128, 4), b256, 0, stream>>>(xc, WkT, nullptr, nullptr, kb, 16384, 512, 512);
  gemm_bf16<0,1,0,1><<<dim3(128, 4), b256, 0, stream>>>(xc, WfT, bfv, nullptr, fv, 16384, 512, 512);
  gates_kernel<<<dim3(4096), b256, 0, stream>>>(xc, WfT, bfv, gates);
  // 4. focal modulation branch
  tr_bf16<<<dim3(16, 8, 16), b256, 0, stream>>>(fv, ftp, 1024, 512);
  focal_conv<<<dim3(8192), b256, 0, stream>>>(ftp, gates, fk0, fk1, accc);
  tr_bf16<<<dim3(8, 16, 16), b256, 0, stream>>>(accc, acct, 512, 1024);
  gemm_bf16<0,1,0,1><<<dim3(128, 4), b256, 0, stream>>>(acct, hwT, h_b, nullptr, vb, 16384, 512, 512);
  // 5. attention + proj (+ residual)
  flash_attn<<<dim3(4, 8, 16), dim3(512), 0, stream>>>(qb, kb, vb, yb);
  gemm_bf16<0,1,1,0><<<dim3(64, 4), b256, 0, stream>>>(yb, WpT, bproj, latents, lat1, 8192, 512, 512);
  // 6. MLP (+ residual) -> d_out (f32)
  ln_kernel<<<dim3(2048), b256, 0, stream>>>(lat1, norm2_w, norm2_b, h2, 8192);
  gemm_bf16<1,1,0,1><<<dim3(64, 16), b256, 0, stream>>>(h2, fc1T, fc1_b, nullptr, a1, 8192, 2048, 512);
  gemm_bf16<0,1,1,0><<<dim3(64, 4),  b256, 0, stream>>>(a1, fc2T, fc2_b, lat1, d_out, 8192, 512, 2048);
  (void)in_sizes; (void)n_in; (void)out_size; (void)ws_size;
}